// Round 5
// baseline (2486077.734 us; speedup 1.0000x reference)
//
#include <hip/hip_runtime.h>
#include <hip/hip_bf16.h>

// ---------------- problem constants ----------------
#define TSEQ 512
#define NB   64
#define NE   256
#define NH   512
#define NG   2048   // 4*NH

// ---------------- workspace layout (bytes) ----------------
static const size_t OFF_W1   = 0;          // 6,291,456
static const size_t OFF_W2   = 6291456;    // 8,388,608
static const size_t OFF_X    = 14680064;   // 16,777,216  (fragment-linear per t)
static const size_t OFF_H1L  = 31457280;   // h1 local plane: 2 dir * 4 slot * 64KB = 524,288
static const size_t OFF_H1A  = 31981568;   // h1 agent plane: 524,288
static const size_t OFF_H2L  = 32505856;   // h2 local plane: 2 dir * 3 slot * 64KB = 393,216
static const size_t OFF_HF   = 32899072;   // 131,072
static const size_t OFF_CNTL = 33030144;   // local tags: 4 sets * 16 rep * 256 * 4B = 64KB
static const size_t OFF_CNTA = 33095680;   // agent tags: 64KB
static const size_t OFF_CHK  = 33161216;   // XCC check table: 4KB   (end 33,165,312)

typedef __bf16 v8bf __attribute__((ext_vector_type(8)));
typedef float  v4f  __attribute__((ext_vector_type(4)));

#define MFMA16(a_, b_, c_) __builtin_amdgcn_mfma_f32_16x16x32_bf16((a_), (b_), (c_), 0, 0, 0)

#define AG_LOAD(p)     __hip_atomic_load((p), __ATOMIC_RELAXED, __HIP_MEMORY_SCOPE_AGENT)
#define AG_STORE(p, v) __hip_atomic_store((p), (v), __ATOMIC_RELAXED, __HIP_MEMORY_SCOPE_AGENT)

// Coherent 16B h-fragment load at AGENT scope (MALL path) — R4-proven.
static __device__ __forceinline__ v8bf load_h8(const __bf16* p) {
    unsigned long long lo = __hip_atomic_load((unsigned long long*)p,     __ATOMIC_RELAXED, __HIP_MEMORY_SCOPE_AGENT);
    unsigned long long hi = __hip_atomic_load((unsigned long long*)p + 1, __ATOMIC_RELAXED, __HIP_MEMORY_SCOPE_AGENT);
    union { unsigned long long q[2]; v8bf v; } u;
    u.q[0] = lo; u.q[1] = hi;
    return u.v;
}

// ---- FAST (intra-XCD) primitives: sc0 = L1-bypass, served by the shared per-XCD L2 ----
static __device__ __forceinline__ void ld16_sc0(v8bf* d, const void* p) {
    asm volatile("global_load_dwordx4 %0, %1, off sc0" : "=v"(*d) : "v"(p) : "memory");
}
static __device__ __forceinline__ int tag_load_sc0(const int* p) {
    int v;
    asm volatile("global_load_dword %0, %1, off sc0\n\ts_waitcnt vmcnt(0)"
                 : "=v"(v) : "v"(p) : "memory");
    return v;
}
static __device__ __forceinline__ void st8_sc0(void* p, unsigned long long v) {
    asm volatile("global_store_dwordx2 %0, %1, off sc0" :: "v"(p), "v"(v) : "memory");
}
static __device__ __forceinline__ void st4_sc0(void* p, int v) {
    asm volatile("global_store_dword %0, %1, off sc0" :: "v"(p), "v"(v) : "memory");
}

static __device__ __forceinline__ unsigned short bf16_bits(float f) {
    __bf16 b = (__bf16)f;
    return __builtin_bit_cast(unsigned short, b);
}

#define SPIN_CAP 65536

// ---------------- phase A: weight convert to fragment-linear bf16 ----------------
__global__ void wconv_kernel(const float* __restrict__ Wf, const float* __restrict__ Uf,
                             const float* __restrict__ Wb, const float* __restrict__ Ub,
                             char* __restrict__ dst, int NC, int KX)
{
    int id = blockIdx.x * 256 + threadIdx.x;
    int j    = id & 7;
    int lane = (id >> 3) & 63;
    int t    = (id >> 9) & 1;
    int rest = id >> 10;            // (dir*64+slice)*NC + c
    int c    = rest % NC;
    int ds   = rest / NC;
    int slice = ds & 63;
    int dirr  = ds >> 6;
    int coll = t * 16 + (lane & 15);
    int k    = c * 32 + (lane >> 4) * 8 + j;
    int gate = coll >> 3, jjj = coll & 7;
    int zcol = gate * 512 + slice * 8 + jjj;
    const float* W = dirr ? Wb : Wf;
    const float* U = dirr ? Ub : Uf;
    float v = (k < KX) ? W[(size_t)k * NG + zcol] : U[(size_t)(k - KX) * NG + zcol];
    ((__bf16*)dst)[id] = (__bf16)v;
}

// ---------------- phase A: embedding gather into fragment-linear X + tag/chk zero ----------------
__global__ void gather_x_kernel(const int* __restrict__ tokens, const float* __restrict__ emb,
                                char* __restrict__ ws)
{
    size_t id = (size_t)blockIdx.x * 256 + threadIdx.x;
    int j  = (int)(id & 7);
    int m  = (int)((id >> 3) & 63);
    int kb = (int)((id >> 9) & 31);
    int t  = (int)(id >> 14);
    int tok = tokens[m * TSEQ + t];
    float v = emb[(size_t)tok * NE + kb * 8 + j];
    ((__bf16*)(ws + OFF_X))[(size_t)t * 16384 + (kb * 64 + m) * 8 + j] = (__bf16)v;
    if (id < 16384) {
        ((int*)(ws + OFF_CNTL))[id] = 0;
        ((int*)(ws + OFF_CNTA))[id] = 0;
    }
    if (id < 1024) ((int*)(ws + OFF_CHK))[id] = 0;
}

// ---------------- phase B: persistent pipelined recurrence ----------------
// Same protocol math as R4 (ring slots, thresholds, drained-tag publish), but the
// SELF-loop exchange (p1/h1 for L1, p2/h2 for L2) runs at intra-XCD L2 latency
// via sc0 ops when the group is verified co-XCD (FAST). Inter-group traffic
// (h1 feed L1->L2, ring guard L2->L1) stays agent-scope but is pipelined off
// the serial path (lagged agent tag, backedge-prefetched polls).
template<int LAYER, bool FAST>
__device__ void run_layer(char* __restrict__ ws, const char* __restrict__ smem,
                          int dir, int slice, int tid,
                          const float* __restrict__ bb)
{
    const int lane = tid & 63;
    const int wv   = tid >> 6;
    const int colc = lane & 15;
    const int q    = lane >> 4;
    const int m0   = wv * 16;
    const int jj   = colc & 7;
    const int hcol = slice * 8 + jj;

    __bf16* h1L = (__bf16*)(ws + OFF_H1L + (size_t)dir * (4 * 65536));
    __bf16* h1A = (__bf16*)(ws + OFF_H1A + (size_t)dir * (4 * 65536));
    __bf16* h2L = (__bf16*)(ws + OFF_H2L + (size_t)dir * (3 * 65536));
    const char* Xfrag = ws + OFF_X;
    __bf16* hfin = (__bf16*)(ws + OFF_HF) + (size_t)dir * (NB * NH);

    int* TL = (int*)(ws + OFF_CNTL);
    int* TA = (int*)(ws + OFF_CNTA);
    const int rep = ((slice << 2) | wv) & 15;
    // self-loop local poll: L1 polls its own set (0), L2 its own set (1)
    int* pollL = TL + (dir * 2 + LAYER) * 4096 + rep * 256 + wv * 64 + lane;
    // agent poll: L1 -> guard on L2's agent tags (set 1); L2 -> h1-ready on L1's agent tags (set 0)
    int* pollAg = TA + (dir * 2 + (LAYER ? 0 : 1)) * 4096 + rep * 256 + wv * 64 + lane;
    int* pubL = TL + (dir * 2 + LAYER) * 4096;
    int* pubA = TA + (dir * 2 + LAYER) * 4096;

    const float bi  = bb[hcol];
    const float bf_ = bb[512 + hcol];
    const float bg  = bb[1024 + hcol];
    const float bo  = bb[1536 + hcol];

    float cst[4] = {0.f, 0.f, 0.f, 0.f};
    const int aoff = (m0 + colc) * 8;   // h-fragment element offset (bf16 units)

    // L2: backedge-prefetched agent tag (response arrives before use at loop top)
    int gvN = LAYER ? AG_LOAD(pollAg) : 0;

    #pragma unroll 1
    for (int s = 0; s < TSEQ; ++s) {
        v4f acc0a = {0,0,0,0}, acc1a = {0,0,0,0};
        v4f acc0b = {0,0,0,0}, acc1b = {0,0,0,0};

        // L1: issue ring-guard agent read at step top; evaluated mid-step (latency hidden)
        int gvG = (LAYER == 0 && s > 3) ? AG_LOAD(pollAg) : 0x7fffffff;

        if (LAYER == 0) {
            // ---- x-part (no step dependency) before the poll ----
            const int xs = dir ? (TSEQ - 1 - s) : s;
            const char* xb = Xfrag + (size_t)xs * 32768;
            #pragma unroll
            for (int c = 0; c < 8; ++c) {
                v8bf a  = *(const v8bf*)(xb + (((4 * c + q) * 64 + m0 + colc) * 16));
                v8bf w0 = *(const v8bf*)(smem + (c * 2 + 0) * 1024 + lane * 16);
                v8bf w1 = *(const v8bf*)(smem + (c * 2 + 1) * 1024 + lane * 16);
                if (c & 1) { acc0b = MFMA16(a, w0, acc0b); acc1b = MFMA16(a, w1, acc1b); }
                else       { acc0a = MFMA16(a, w0, acc0a); acc1a = MFMA16(a, w1, acc1a); }
            }
            // ---- fast self-loop poll: peers' h1[s-1] published ----
            if (s > 0) {
                int it = 0;
                while (true) {
                    int v1 = FAST ? tag_load_sc0(pollL) : AG_LOAD(pollL);
                    if (__all(v1 >= s) || ++it > SPIN_CAP) break;
                }
            }
            // ---- ring guard for h1A overwrite (agent, prefetched; rarely blocks) ----
            if (s > 3 && !__all(gvG >= s - 3)) {
                int it = 0;
                while (true) {
                    int v2 = AG_LOAD(pollAg);
                    if (__all(v2 >= s - 3) || ++it > SPIN_CAP) break;
                }
            }
            // ---- h1[s-1]-dependent MFMA work (fast local reads) ----
            if (s > 0) {
                const __bf16* hb = h1L + (size_t)((s - 1) & 3) * 32768;
                v8bf ah[16];
                if (FAST) {
                    #pragma unroll
                    for (int c = 0; c < 16; ++c)
                        ld16_sc0(&ah[c], hb + (4 * c + q) * 512 + aoff);
                    asm volatile("s_waitcnt vmcnt(0)" ::: "memory");
                } else {
                    #pragma unroll
                    for (int c = 0; c < 16; ++c)
                        ah[c] = load_h8(hb + (4 * c + q) * 512 + aoff);
                }
                __builtin_amdgcn_sched_barrier(0);
                #pragma unroll
                for (int c = 0; c < 16; ++c) {
                    v8bf w0 = *(const v8bf*)(smem + ((8 + c) * 2 + 0) * 1024 + lane * 16);
                    v8bf w1 = *(const v8bf*)(smem + ((8 + c) * 2 + 1) * 1024 + lane * 16);
                    if (c & 1) { acc0b = MFMA16(ah[c], w0, acc0b); acc1b = MFMA16(ah[c], w1, acc1b); }
                    else       { acc0a = MFMA16(ah[c], w0, acc0a); acc1a = MFMA16(ah[c], w1, acc1a); }
                }
            }
        } else {
            // ---- h1[s] ready check: prefetched tag (value observed BEFORE issuing loads) ----
            if (!__all(gvN >= s + 1)) {
                int it = 0;
                while (true) {
                    gvN = AG_LOAD(pollAg);
                    if (__all(gvN >= s + 1) || ++it > SPIN_CAP) break;
                }
            }
            const __bf16* hb1 = h1A + (size_t)(s & 3) * 32768;
            v8bf a0[16], a1[16];
            #pragma unroll
            for (int c = 0; c < 16; ++c)
                a0[c] = load_h8(hb1 + (4 * c + q) * 512 + aoff);
            if (s > 0) {
                // ---- fast self-loop poll: peers' h2[s-1] ----
                {
                    int it = 0;
                    while (true) {
                        int v2 = FAST ? tag_load_sc0(pollL) : AG_LOAD(pollL);
                        if (__all(v2 >= s) || ++it > SPIN_CAP) break;
                    }
                }
                const __bf16* hb2 = h2L + (size_t)((s - 1) % 3) * 32768;
                if (FAST) {
                    #pragma unroll
                    for (int c = 0; c < 16; ++c)
                        ld16_sc0(&a1[c], hb2 + (4 * c + q) * 512 + aoff);
                    asm volatile("s_waitcnt vmcnt(0)" ::: "memory");
                } else {
                    #pragma unroll
                    for (int c = 0; c < 16; ++c)
                        a1[c] = load_h8(hb2 + (4 * c + q) * 512 + aoff);
                }
            }
            __builtin_amdgcn_sched_barrier(0);
            #pragma unroll
            for (int c = 0; c < 16; ++c) {
                v8bf w0 = *(const v8bf*)(smem + (c * 2 + 0) * 1024 + lane * 16);
                v8bf w1 = *(const v8bf*)(smem + (c * 2 + 1) * 1024 + lane * 16);
                if (c & 1) { acc0b = MFMA16(a0[c], w0, acc0b); acc1b = MFMA16(a0[c], w1, acc1b); }
                else       { acc0a = MFMA16(a0[c], w0, acc0a); acc1a = MFMA16(a0[c], w1, acc1a); }
            }
            if (s > 0) {
                #pragma unroll
                for (int c = 0; c < 16; ++c) {
                    v8bf w0 = *(const v8bf*)(smem + ((16 + c) * 2 + 0) * 1024 + lane * 16);
                    v8bf w1 = *(const v8bf*)(smem + ((16 + c) * 2 + 1) * 1024 + lane * 16);
                    if (c & 1) { acc0b = MFMA16(a1[c], w0, acc0b); acc1b = MFMA16(a1[c], w1, acc1b); }
                    else       { acc0a = MFMA16(a1[c], w0, acc0a); acc1a = MFMA16(a1[c], w1, acc1a); }
                }
            }
        }

        v4f z0 = acc0a + acc0b;   // gates i (cols 0-7) / f (cols 8-15)
        v4f z1 = acc1a + acc1b;   // gates g / o

        // ---- gate nonlinearity; lanes col and col^8 exchange ----
        float hv[4];
        #pragma unroll
        for (int r = 0; r < 4; ++r) {
            float p0 = __shfl_xor(z0[r], 8, 64);
            float p1 = __shfl_xor(z1[r], 8, 64);
            float zi, zf, zg, zo;
            if (colc < 8) { zi = z0[r]; zf = p0;    zg = z1[r]; zo = p1;    }
            else          { zi = p0;    zf = z0[r]; zg = p1;    zo = z1[r]; }
            zi += bi; zf += bf_; zg += bg; zo += bo;
            float gi = 1.f / (1.f + __expf(-zi));
            float gf = 1.f / (1.f + __expf(-zf));
            float gg = 1.f - 2.f / (1.f + __expf(2.f * zg));   // tanh
            float go = 1.f / (1.f + __expf(-zo));
            float cn = gf * cst[r] + gi * gg;
            cst[r] = cn;
            float th = 1.f - 2.f / (1.f + __expf(2.f * cn));   // tanh
            hv[r] = go * th;
        }

        // ---- coalesced h publication: 4x4 lane transpose -> 16B per active lane (R4) ----
        unsigned long long lo = 0, hi = 0;
        const bool act = ((colc & 1) == 0) && (colc < 8);
        const int mrow = m0 + q * 4 + (colc >> 1);
        {
            unsigned u0, u1, u2, u3;
            {
                float pv0 = __shfl_xor(hv[0], 1, 64);
                float pv1 = __shfl_xor(hv[1], 1, 64);
                float pv2 = __shfl_xor(hv[2], 1, 64);
                float pv3 = __shfl_xor(hv[3], 1, 64);
                u0 = (unsigned)bf16_bits(hv[0]) | ((unsigned)bf16_bits(pv0) << 16);
                u1 = (unsigned)bf16_bits(hv[1]) | ((unsigned)bf16_bits(pv1) << 16);
                u2 = (unsigned)bf16_bits(hv[2]) | ((unsigned)bf16_bits(pv2) << 16);
                u3 = (unsigned)bf16_bits(hv[3]) | ((unsigned)bf16_bits(pv3) << 16);
            }
            const bool sel1 = (colc & 2) != 0;
            const bool sel2 = (colc & 4) != 0;
            unsigned t;
            t = __shfl_xor(sel1 ? u0 : u1, 2, 64); if (sel1) u0 = t; else u1 = t;
            t = __shfl_xor(sel1 ? u2 : u3, 2, 64); if (sel1) u2 = t; else u3 = t;
            t = __shfl_xor(sel2 ? u0 : u2, 4, 64); if (sel2) u0 = t; else u2 = t;
            t = __shfl_xor(sel2 ? u1 : u3, 4, 64); if (sel2) u1 = t; else u3 = t;
            lo = (unsigned long long)u0 | ((unsigned long long)u1 << 32);
            hi = (unsigned long long)u2 | ((unsigned long long)u3 << 32);
        }
        const size_t off8 = (size_t)(slice * 64 + mrow) * 8;   // bf16 units
        __bf16* dA = h1A + (size_t)(s & 3) * 32768 + off8;     // L1 agent copy dest
        if (act) {
            __bf16* dL = (LAYER ? h2L + (size_t)(s % 3) * 32768
                                : h1L + (size_t)(s & 3) * 32768) + off8;
            if (FAST) { st8_sc0(dL, lo); st8_sc0((char*)dL + 8, hi); }
            else {
                AG_STORE((unsigned long long*)dL,     lo);
                AG_STORE((unsigned long long*)dL + 1, hi);
            }
        }
        if (LAYER == 1 && s == TSEQ - 1 && colc < 8) {
            #pragma unroll
            for (int r = 0; r < 4; ++r)
                hfin[(size_t)(m0 + q * 4 + r) * NH + hcol] = (__bf16)hv[r];
        }

        // drain local stores (and last step's agent stores), then publish tags
        asm volatile("s_waitcnt vmcnt(0)" ::: "memory");
        if (lane < 16) {
            int* tpL = pubL + lane * 256 + wv * 64 + slice;
            if (FAST) st4_sc0(tpL, s + 1);
            else      AG_STORE(tpL, s + 1);
            // agent tag: L1 lagged by one step (covers stores drained above); L2 immediate
            AG_STORE(pubA + lane * 256 + wv * 64 + slice, LAYER ? (s + 1) : s);
        }
        // L1: issue agent-plane copy of h1[s] (fire-and-forget; drained next step)
        if (LAYER == 0 && act) {
            AG_STORE((unsigned long long*)dA,     lo);
            AG_STORE((unsigned long long*)dA + 1, hi);
        }
        // L2: prefetch h1-ready tag for next step across the backedge
        if (LAYER == 1) gvN = AG_LOAD(pollAg);
    }

    // L1 epilogue: final lagged agent tag so L2 can reach step 511
    if (LAYER == 0) {
        asm volatile("s_waitcnt vmcnt(0)" ::: "memory");
        if (lane < 16)
            AG_STORE(pubA + lane * 256 + wv * 64 + slice, TSEQ);
    }
}

__global__ __launch_bounds__(256, 1) void lstm_persist(
    char* __restrict__ ws,
    const float* __restrict__ b1f, const float* __restrict__ b2f,
    const float* __restrict__ b1b, const float* __restrict__ b2b)
{
    const int tid = threadIdx.x;
    const int bid = blockIdx.x;          // 512 wgs launched
    if ((bid & 7) >= 4) return;          // ghosts keep XCDs 4..7 out of the way
    const int g     = bid & 7;           // 0..3 -> (dir, layer); co-XCD if placement = bid%8
    const int dir   = g >> 1;
    const int layer = g & 1;
    const int slice = bid >> 3;          // 0..63

    // publish our XCD id and check in (before staging so arrival overlaps staging)
    int* chk = (int*)(ws + OFF_CHK);
    unsigned xcc = 0;
    asm volatile("s_getreg_b32 %0, hwreg(HW_REG_XCC_ID)" : "=s"(xcc));
    if (tid == 0) {
        AG_STORE(chk + g * 64 + slice, (int)xcc + 1);
        __hip_atomic_fetch_add(chk + 256, 1, __ATOMIC_RELAXED, __HIP_MEMORY_SCOPE_AGENT);
    }

    const int NC = layer ? 32 : 24;
    const int wbytes = NC * 2048;        // 48KB (L1) / 64KB (L2)
    __shared__ char smem[65536];
    {
        const char* wsrc = ws + (layer ? OFF_W2 : OFF_W1)
                         + (size_t)(dir * 64 + slice) * (size_t)wbytes;
        for (int i = tid * 16; i < wbytes; i += 256 * 16)
            *(uint4*)(smem + i) = *(const uint4*)(wsrc + i);
    }
    __syncthreads();

    // wait for all 256 real wgs, then verify this group is co-XCD (else agent fallback)
    bool fast = false;
    {
        int it = 0, cnt = 0;
        do { cnt = AG_LOAD(chk + 256); } while (cnt < 256 && ++it < (1 << 20));
        if (cnt >= 256) {
            int my = AG_LOAD(chk + g * 64 + (tid & 63));
            fast = __all(my == __shfl(my, 0, 64)) && (my != 0);
        }
    }

    const float* bb = layer ? (dir ? b2b : b2f) : (dir ? b1b : b1f);
    if (layer == 0) {
        if (fast) run_layer<0, true >(ws, smem, dir, slice, tid, bb);
        else      run_layer<0, false>(ws, smem, dir, slice, tid, bb);
    } else {
        if (fast) run_layer<1, true >(ws, smem, dir, slice, tid, bb);
        else      run_layer<1, false>(ws, smem, dir, slice, tid, bb);
    }
}

// ---------------- phase C: dense head [64,1024]@[1024,5]+bd ----------------
__global__ void head_kernel(const char* __restrict__ ws, const float* __restrict__ Wd,
                            const float* __restrict__ bd, float* __restrict__ out)
{
    int b = blockIdx.x;
    int lane = threadIdx.x;   // 64
    const __bf16* hfF = (const __bf16*)(ws + OFF_HF) + (size_t)b * NH;
    const __bf16* hfB = (const __bf16*)(ws + OFF_HF) + (size_t)(NB * NH) + (size_t)b * NH;
    #pragma unroll
    for (int o = 0; o < 5; ++o) {
        float sum = 0.f;
        for (int k = lane; k < 2 * NH; k += 64) {
            float fv = (k < NH) ? (float)hfF[k] : (float)hfB[k - NH];
            sum += fv * Wd[(size_t)k * 5 + o];
        }
        #pragma unroll
        for (int off = 32; off > 0; off >>= 1) sum += __shfl_down(sum, off, 64);
        if (lane == 0) out[b * 5 + o] = sum + bd[o];
    }
}

// ---------------- launch ----------------
extern "C" void kernel_launch(void* const* d_in, const int* in_sizes, int n_in,
                              void* d_out, int out_size, void* d_ws, size_t ws_size,
                              hipStream_t stream)
{
    const int*   tokens = (const int*)  d_in[0];
    const float* emb    = (const float*)d_in[1];
    const float* W1f    = (const float*)d_in[2];
    const float* U1f    = (const float*)d_in[3];
    const float* b1f    = (const float*)d_in[4];
    const float* W2f    = (const float*)d_in[5];
    const float* U2f    = (const float*)d_in[6];
    const float* b2f    = (const float*)d_in[7];
    const float* W1b    = (const float*)d_in[8];
    const float* U1b    = (const float*)d_in[9];
    const float* b1b    = (const float*)d_in[10];
    const float* W2b    = (const float*)d_in[11];
    const float* U2b    = (const float*)d_in[12];
    const float* b2b    = (const float*)d_in[13];
    const float* Wd     = (const float*)d_in[14];
    const float* bd     = (const float*)d_in[15];
    char* ws = (char*)d_ws;

    wconv_kernel<<<12288, 256, 0, stream>>>(W1f, U1f, W1b, U1b, ws + OFF_W1, 24, 256);
    wconv_kernel<<<16384, 256, 0, stream>>>(W2f, U2f, W2b, U2b, ws + OFF_W2, 32, 512);
    gather_x_kernel<<<32768, 256, 0, stream>>>(tokens, emb, ws);
    lstm_persist<<<512, 256, 0, stream>>>(ws, b1f, b2f, b1b, b2b);
    head_kernel<<<NB, 64, 0, stream>>>(ws, Wd, bd, (float*)d_out);
}

// Round 6
// 20057.761 us; speedup vs baseline: 123.9459x; 123.9459x over previous
//
#include <hip/hip_runtime.h>
#include <hip/hip_bf16.h>

// ---------------- problem constants ----------------
#define TSEQ 512
#define NB   64
#define NE   256
#define NH   512
#define NG   2048   // 4*NH

// ---------------- workspace layout (bytes) ----------------
static const size_t OFF_W1   = 0;          // 6,291,456
static const size_t OFF_W2   = 6291456;    // 8,388,608
static const size_t OFF_X    = 14680064;   // 16,777,216 (fragment-linear per t)
static const size_t OFF_H1L  = 31457280;   // h1 fast plane: 2 dir * 2 slot * 64KB = 262,144
static const size_t OFF_H1A  = 31719424;   // h1 agent plane: 2 dir * 4 slot * 64KB = 524,288
static const size_t OFF_H2L  = 32243712;   // h2 fast plane: 2 dir * 2 slot * 64KB = 262,144
static const size_t OFF_H2A  = 32505856;   // h2 agent plane: 2 dir * 3 slot * 64KB = 393,216
static const size_t OFF_HF   = 32899072;   // 131,072
static const size_t OFF_CNTA = 33030144;   // agent tags: 4 sets * 16 rep * 256 * 4B = 64KB
static const size_t OFF_FCT  = 33095680;   // fast counters: 128 * 64B = 8KB
static const size_t OFF_CHK  = 33103872;   // XCC check table + guaranteed-zero pad: 4KB
// end = 33,107,968  (< R5's proven 33,165,312)

typedef __bf16 v8bf __attribute__((ext_vector_type(8)));
typedef float  v4f  __attribute__((ext_vector_type(4)));

#define MFMA16(a_, b_, c_) __builtin_amdgcn_mfma_f32_16x16x32_bf16((a_), (b_), (c_), 0, 0, 0)

#define AG_LOAD(p)     __hip_atomic_load((p), __ATOMIC_RELAXED, __HIP_MEMORY_SCOPE_AGENT)
#define AG_STORE(p, v) __hip_atomic_store((p), (v), __ATOMIC_RELAXED, __HIP_MEMORY_SCOPE_AGENT)
// Workgroup-scope atomics on global memory: RMWs cannot be serviced by L1 —
// they execute at the XCD's L2 (no device-scope cache bypass bits emitted).
// That is the intra-XCD coherence point the fast path needs.
#define WG_XCHG(p, v)  __hip_atomic_exchange((p), (v), __ATOMIC_RELAXED, __HIP_MEMORY_SCOPE_WORKGROUP)
#define WG_OR(p, z)    __hip_atomic_fetch_or((p), (z), __ATOMIC_RELAXED, __HIP_MEMORY_SCOPE_WORKGROUP)
#define WG_ADD1(p)     __hip_atomic_fetch_add((p), 1, __ATOMIC_RELAXED, __HIP_MEMORY_SCOPE_WORKGROUP)

#define FAST_BUDGET 4096
#define SPIN_CAP    (1 << 21)   // deadman only; unreachable if protocol algebra holds

// Coherent 16B h-fragment load at AGENT scope (MALL path) — R0..R4 proven.
static __device__ __forceinline__ v8bf load_h8(const __bf16* p) {
    unsigned long long lo = AG_LOAD((unsigned long long*)p);
    unsigned long long hi = AG_LOAD((unsigned long long*)p + 1);
    union { unsigned long long q[2]; v8bf v; } u;
    u.q[0] = lo; u.q[1] = hi;
    return u.v;
}

// 16B fragment read executed at L2 via atomic fetch_or with a RUNTIME zero
// (zv loaded from guaranteed-zero memory so the compiler cannot fold or-0
// into a plain — L1-cacheable, stale — load). Compiler manages latency/regs.
static __device__ __forceinline__ v8bf load_h8_l2(const __bf16* p, unsigned long long zv) {
    unsigned long long lo = WG_OR((unsigned long long*)p, zv);
    unsigned long long hi = WG_OR((unsigned long long*)p + 1, zv);
    union { unsigned long long q[2]; v8bf v; } u;
    u.q[0] = lo; u.q[1] = hi;
    return u.v;
}

static __device__ __forceinline__ unsigned short bf16_bits(float f) {
    __bf16 b = (__bf16)f;
    return __builtin_bit_cast(unsigned short, b);
}

// ---------------- phase A: weight convert to fragment-linear bf16 ----------------
__global__ void wconv_kernel(const float* __restrict__ Wf, const float* __restrict__ Uf,
                             const float* __restrict__ Wb, const float* __restrict__ Ub,
                             char* __restrict__ dst, int NC, int KX)
{
    int id = blockIdx.x * 256 + threadIdx.x;
    int j    = id & 7;
    int lane = (id >> 3) & 63;
    int t    = (id >> 9) & 1;
    int rest = id >> 10;            // (dir*64+slice)*NC + c
    int c    = rest % NC;
    int ds   = rest / NC;
    int slice = ds & 63;
    int dirr  = ds >> 6;
    int coll = t * 16 + (lane & 15);
    int k    = c * 32 + (lane >> 4) * 8 + j;
    int gate = coll >> 3, jjj = coll & 7;
    int zcol = gate * 512 + slice * 8 + jjj;
    const float* W = dirr ? Wb : Wf;
    const float* U = dirr ? Ub : Uf;
    float v = (k < KX) ? W[(size_t)k * NG + zcol] : U[(size_t)(k - KX) * NG + zcol];
    ((__bf16*)dst)[id] = (__bf16)v;
}

// ---------------- phase A: embedding gather into fragment-linear X + tag/cnt/chk zero ----------------
__global__ void gather_x_kernel(const int* __restrict__ tokens, const float* __restrict__ emb,
                                char* __restrict__ ws)
{
    size_t id = (size_t)blockIdx.x * 256 + threadIdx.x;
    int j  = (int)(id & 7);
    int m  = (int)((id >> 3) & 63);
    int kb = (int)((id >> 9) & 31);
    int t  = (int)(id >> 14);
    int tok = tokens[m * TSEQ + t];
    float v = emb[(size_t)tok * NE + kb * 8 + j];
    ((__bf16*)(ws + OFF_X))[(size_t)t * 16384 + (kb * 64 + m) * 8 + j] = (__bf16)v;
    // zero agent tags + fast counters + chk table (contiguous 77,824 B)
    if (id < 19456) ((int*)(ws + OFF_CNTA))[id] = 0;
}

// ---------------- phase B: persistent pipelined recurrence ----------------
// R0's proven protocol algebra with a dual-plane, per-operation-degradable fast
// path. Producers ALWAYS publish both planes each step:
//   fast plane:  atomic_exchange (L2-executed)      — drained by vmcnt(2)
//   agent plane: agent stores (MALL)                — drained by NEXT step's wait
//   fast tag:    per-(wave,slot) monotone counter (atomic add at L2)
//   agent tag:   value-semantics v => agent h[v-1] visible (v=s fast / v=s+1 demoted)
// Consumers probe the fast path (counter poll, FAST_BUDGET); on expiry they
// permanently demote to the agent path. Any mixture is deadlock-free and correct.
template<int LAYER>
__device__ void run_layer(char* __restrict__ ws, const char* __restrict__ smem,
                          int dir, int slice, int tid,
                          const float* __restrict__ bb, int fl0, unsigned long long zv)
{
    const int lane = tid & 63;
    const int wv   = tid >> 6;
    const int colc = lane & 15;
    const int q    = lane >> 4;
    const int m0   = wv * 16;
    const int jj   = colc & 7;
    const int hcol = slice * 8 + jj;
    const int izv  = (int)zv;           // runtime zero (int)

    __bf16* h1L = (__bf16*)(ws + OFF_H1L + (size_t)dir * (2 * 65536));
    __bf16* h1A = (__bf16*)(ws + OFF_H1A + (size_t)dir * (4 * 65536));
    __bf16* h2L = (__bf16*)(ws + OFF_H2L + (size_t)dir * (2 * 65536));
    __bf16* h2A = (__bf16*)(ws + OFF_H2A + (size_t)dir * (3 * 65536));
    const char* Xfrag = ws + OFF_X;
    __bf16* hfin = (__bf16*)(ws + OFF_HF) + (size_t)dir * (NB * NH);

    // agent tags (R0-style x16 replicas)
    int* TA = (int*)(ws + OFF_CNTA);
    const int rep = ((slice << 2) | wv) & 15;
    int* pollSelfA  = TA + (dir * 2 + LAYER) * 4096 + rep * 256 + wv * 64 + lane;           // own layer
    int* pollOtherA = TA + (dir * 2 + (LAYER ? 0 : 1)) * 4096 + rep * 256 + wv * 64 + lane; // other layer
    int* pubA = TA + (dir * 2 + LAYER) * 4096;

    // fast counters: one 64B line per (dir,layer,wave,slot)
    int* FC = (int*)(ws + OFF_FCT) + (size_t)((dir * 2 + LAYER) * 32 + wv * 8) * 16;

    const float bi  = bb[hcol];
    const float bf_ = bb[512 + hcol];
    const float bg  = bb[1024 + hcol];
    const float bo  = bb[1536 + hcol];

    float cst[4] = {0.f, 0.f, 0.f, 0.f};
    const int aoff = (m0 + colc) * 8;   // h-fragment element offset (bf16 units)

    int fl = fl0;                        // fast-live (wave-uniform), demotable once

    // L2: backedge-prefetched cross agent tag
    int gvN = LAYER ? AG_LOAD(pollOtherA) : 0;

    #pragma unroll 1
    for (int s = 0; s < TSEQ; ++s) {
        v4f acc0a = {0,0,0,0}, acc1a = {0,0,0,0};
        v4f acc0b = {0,0,0,0}, acc1b = {0,0,0,0};

        // L1: issue ring-guard agent read at step top; evaluated mid-step (latency hidden)
        int gvG = (LAYER == 0 && s > 3) ? AG_LOAD(pollOtherA) : 0x7fffffff;

        if (LAYER == 0) {
            // ---- x-part (no step dependency) before any poll ----
            const int xs = dir ? (TSEQ - 1 - s) : s;
            const char* xb = Xfrag + (size_t)xs * 32768;
            #pragma unroll
            for (int c = 0; c < 8; ++c) {
                v8bf a  = *(const v8bf*)(xb + (((4 * c + q) * 64 + m0 + colc) * 16));
                v8bf w0 = *(const v8bf*)(smem + (c * 2 + 0) * 1024 + lane * 16);
                v8bf w1 = *(const v8bf*)(smem + (c * 2 + 1) * 1024 + lane * 16);
                if (c & 1) { acc0b = MFMA16(a, w0, acc0b); acc1b = MFMA16(a, w1, acc1b); }
                else       { acc0a = MFMA16(a, w0, acc0a); acc1a = MFMA16(a, w1, acc1a); }
            }
            // ---- self poll: peers' h1[s-1] published ----
            if (s > 0) {
                if (fl) {
                    const int need = 64 * (((s - 1) >> 3) + 1);
                    int* fcp = FC + ((s - 1) & 7) * 16;
                    int it = 0;
                    while (true) {
                        int c0 = (lane == 0) ? (int)WG_OR(fcp, izv) : 0;
                        c0 = __shfl(c0, 0, 64);
                        if (c0 >= need) break;
                        if (++it >= FAST_BUDGET) { fl = 0; break; }
                    }
                }
                if (!fl) {
                    int it = 0;
                    while (true) {
                        int v1 = AG_LOAD(pollSelfA);
                        if (__all(v1 >= s) || ++it > SPIN_CAP) break;
                    }
                }
            }
            // ---- h1A ring-4 guard (agent, prefetched; rarely blocks) ----
            if (s > 3 && !__all(gvG >= s - 3)) {
                int it = 0;
                while (true) {
                    int v2 = AG_LOAD(pollOtherA);
                    if (__all(v2 >= s - 3) || ++it > SPIN_CAP) break;
                }
            }
            // ---- h1[s-1]-dependent MFMA work ----
            if (s > 0) {
                v8bf ah[16];
                if (fl) {
                    const __bf16* hb = h1L + (size_t)((s - 1) & 1) * 32768;
                    #pragma unroll
                    for (int c = 0; c < 16; ++c)
                        ah[c] = load_h8_l2(hb + (4 * c + q) * 512 + aoff, zv);
                } else {
                    const __bf16* hb = h1A + (size_t)((s - 1) & 3) * 32768;
                    #pragma unroll
                    for (int c = 0; c < 16; ++c)
                        ah[c] = load_h8(hb + (4 * c + q) * 512 + aoff);
                }
                __builtin_amdgcn_sched_barrier(0);
                #pragma unroll
                for (int c = 0; c < 16; ++c) {
                    v8bf w0 = *(const v8bf*)(smem + ((8 + c) * 2 + 0) * 1024 + lane * 16);
                    v8bf w1 = *(const v8bf*)(smem + ((8 + c) * 2 + 1) * 1024 + lane * 16);
                    if (c & 1) { acc0b = MFMA16(ah[c], w0, acc0b); acc1b = MFMA16(ah[c], w1, acc1b); }
                    else       { acc0a = MFMA16(ah[c], w0, acc0a); acc1a = MFMA16(ah[c], w1, acc1a); }
                }
            }
        } else {
            // ---- cross feed: h1A[s] visible <=> agentTag_L1 >= s+1 (prefetched) ----
            if (!__all(gvN >= s + 1)) {
                int it = 0;
                while (true) {
                    gvN = AG_LOAD(pollOtherA);
                    if (__all(gvN >= s + 1) || ++it > SPIN_CAP) break;
                }
            }
            const __bf16* hb1 = h1A + (size_t)(s & 3) * 32768;
            v8bf a0[16], a1[16];
            #pragma unroll
            for (int c = 0; c < 16; ++c)
                a0[c] = load_h8(hb1 + (4 * c + q) * 512 + aoff);
            if (s > 0) {
                // ---- self poll: peers' h2[s-1] ----
                if (fl) {
                    const int need = 64 * (((s - 1) >> 3) + 1);
                    int* fcp = FC + ((s - 1) & 7) * 16;
                    int it = 0;
                    while (true) {
                        int c0 = (lane == 0) ? (int)WG_OR(fcp, izv) : 0;
                        c0 = __shfl(c0, 0, 64);
                        if (c0 >= need) break;
                        if (++it >= FAST_BUDGET) { fl = 0; break; }
                    }
                }
                if (!fl) {
                    int it = 0;
                    while (true) {
                        int v2 = AG_LOAD(pollSelfA);
                        if (__all(v2 >= s) || ++it > SPIN_CAP) break;
                    }
                }
                if (fl) {
                    const __bf16* hb2 = h2L + (size_t)((s - 1) & 1) * 32768;
                    #pragma unroll
                    for (int c = 0; c < 16; ++c)
                        a1[c] = load_h8_l2(hb2 + (4 * c + q) * 512 + aoff, zv);
                } else {
                    const __bf16* hb2 = h2A + (size_t)((s - 1) % 3) * 32768;
                    #pragma unroll
                    for (int c = 0; c < 16; ++c)
                        a1[c] = load_h8(hb2 + (4 * c + q) * 512 + aoff);
                }
            }
            __builtin_amdgcn_sched_barrier(0);
            #pragma unroll
            for (int c = 0; c < 16; ++c) {
                v8bf w0 = *(const v8bf*)(smem + (c * 2 + 0) * 1024 + lane * 16);
                v8bf w1 = *(const v8bf*)(smem + (c * 2 + 1) * 1024 + lane * 16);
                if (c & 1) { acc0b = MFMA16(a0[c], w0, acc0b); acc1b = MFMA16(a0[c], w1, acc1b); }
                else       { acc0a = MFMA16(a0[c], w0, acc0a); acc1a = MFMA16(a0[c], w1, acc1a); }
            }
            if (s > 0) {
                #pragma unroll
                for (int c = 0; c < 16; ++c) {
                    v8bf w0 = *(const v8bf*)(smem + ((16 + c) * 2 + 0) * 1024 + lane * 16);
                    v8bf w1 = *(const v8bf*)(smem + ((16 + c) * 2 + 1) * 1024 + lane * 16);
                    if (c & 1) { acc0b = MFMA16(a1[c], w0, acc0b); acc1b = MFMA16(a1[c], w1, acc1b); }
                    else       { acc0a = MFMA16(a1[c], w0, acc0a); acc1a = MFMA16(a1[c], w1, acc1a); }
                }
            }
        }

        v4f z0 = acc0a + acc0b;   // gates i (cols 0-7) / f (cols 8-15)
        v4f z1 = acc1a + acc1b;   // gates g / o

        // ---- gate nonlinearity; lanes col and col^8 exchange ----
        float hv[4];
        #pragma unroll
        for (int r = 0; r < 4; ++r) {
            float p0 = __shfl_xor(z0[r], 8, 64);
            float p1 = __shfl_xor(z1[r], 8, 64);
            float zi, zf, zg, zo;
            if (colc < 8) { zi = z0[r]; zf = p0;    zg = z1[r]; zo = p1;    }
            else          { zi = p0;    zf = z0[r]; zg = p1;    zo = z1[r]; }
            zi += bi; zf += bf_; zg += bg; zo += bo;
            float gi = 1.f / (1.f + __expf(-zi));
            float gf = 1.f / (1.f + __expf(-zf));
            float gg = 1.f - 2.f / (1.f + __expf(2.f * zg));   // tanh
            float go = 1.f / (1.f + __expf(-zo));
            float cn = gf * cst[r] + gi * gg;
            cst[r] = cn;
            float th = 1.f - 2.f / (1.f + __expf(2.f * cn));   // tanh
            hv[r] = go * th;
        }

        // ---- coalesced publication: 4x4 lane transpose -> 16B per active lane (R4) ----
        unsigned long long lo = 0, hi = 0;
        const bool act = ((colc & 1) == 0) && (colc < 8);
        const int mrow = m0 + q * 4 + (colc >> 1);
        {
            unsigned u0, u1, u2, u3;
            {
                float pv0 = __shfl_xor(hv[0], 1, 64);
                float pv1 = __shfl_xor(hv[1], 1, 64);
                float pv2 = __shfl_xor(hv[2], 1, 64);
                float pv3 = __shfl_xor(hv[3], 1, 64);
                u0 = (unsigned)bf16_bits(hv[0]) | ((unsigned)bf16_bits(pv0) << 16);
                u1 = (unsigned)bf16_bits(hv[1]) | ((unsigned)bf16_bits(pv1) << 16);
                u2 = (unsigned)bf16_bits(hv[2]) | ((unsigned)bf16_bits(pv2) << 16);
                u3 = (unsigned)bf16_bits(hv[3]) | ((unsigned)bf16_bits(pv3) << 16);
            }
            const bool sel1 = (colc & 2) != 0;
            const bool sel2 = (colc & 4) != 0;
            unsigned t;
            t = __shfl_xor(sel1 ? u0 : u1, 2, 64); if (sel1) u0 = t; else u1 = t;
            t = __shfl_xor(sel1 ? u2 : u3, 2, 64); if (sel1) u2 = t; else u3 = t;
            t = __shfl_xor(sel2 ? u0 : u2, 4, 64); if (sel2) u0 = t; else u2 = t;
            t = __shfl_xor(sel2 ? u1 : u3, 4, 64); if (sel2) u1 = t; else u3 = t;
            lo = (unsigned long long)u0 | ((unsigned long long)u1 << 32);
            hi = (unsigned long long)u2 | ((unsigned long long)u3 << 32);
        }
        const size_t off8 = (size_t)(slice * 64 + mrow) * 8;   // bf16 units

        // kernel-boundary output first (flushed at kernel end; keeps drain-queue tail clean)
        if (LAYER == 1 && s == TSEQ - 1 && colc < 8) {
            #pragma unroll
            for (int r = 0; r < 4; ++r)
                hfin[(size_t)(m0 + q * 4 + r) * NH + hcol] = (__bf16)hv[r];
        }

        // (1) fast-plane data (L2-executed atomic exchange)
        if (act) {
            __bf16* dF = (LAYER ? h2L + (size_t)(s & 1) * 32768
                                : h1L + (size_t)(s & 1) * 32768) + off8;
            WG_XCHG((unsigned long long*)dF,     lo);
            WG_XCHG((unsigned long long*)dF + 1, hi);
        }
        __builtin_amdgcn_sched_barrier(0);
        // (2) agent-plane data (MALL; ack deferred to next step's drain in fast regime)
        if (act) {
            __bf16* dA = (LAYER ? h2A + (size_t)(s % 3) * 32768
                                : h1A + (size_t)(s & 3) * 32768) + off8;
            AG_STORE((unsigned long long*)dA,     lo);
            AG_STORE((unsigned long long*)dA + 1, hi);
        }
        // (3) drain: fast regime waits only the fast swaps (2 newest ops are the
        //     agent stores and may float); demoted regime waits everything.
        if (fl) asm volatile("s_waitcnt vmcnt(2)" ::: "memory");
        else    asm volatile("s_waitcnt vmcnt(0)" ::: "memory");
        // (4) tags: fast counter (covers fast h[s]); agent tag value-semantics
        //     v => agent h[v-1] visible: fast publishes s (lagged), demoted s+1.
        if (lane == 0) WG_ADD1(FC + (s & 7) * 16);
        if (lane < 16)
            AG_STORE(pubA + lane * 256 + wv * 64 + slice, fl ? s : s + 1);

        // L2: prefetch next step's cross tag across the backedge
        if (LAYER == 1) gvN = AG_LOAD(pollOtherA);
    }

    // L1 epilogue: final agent tag so L2 can reach step 511 (h1A[511] drained here)
    if (LAYER == 0) {
        asm volatile("s_waitcnt vmcnt(0)" ::: "memory");
        if (lane < 16)
            AG_STORE(pubA + lane * 256 + wv * 64 + slice, TSEQ);
    }
}

__global__ __launch_bounds__(256, 2) void lstm_persist(
    char* __restrict__ ws,
    const float* __restrict__ b1f, const float* __restrict__ b2f,
    const float* __restrict__ b1b, const float* __restrict__ b2b)
{
    const int tid = threadIdx.x;
    const int bid = blockIdx.x;          // 512 wgs launched
    if ((bid & 7) >= 4) return;          // ghosts keep XCDs 4..7 clear (if placement = bid%8)
    const int g     = bid & 7;           // 0..3 -> (dir, layer)
    const int dir   = g >> 1;
    const int layer = g & 1;
    const int slice = bid >> 3;          // 0..63

    // publish our XCD id and check in (arrival overlaps weight staging)
    int* chk = (int*)(ws + OFF_CHK);
    unsigned xcc = 0;
    asm volatile("s_getreg_b32 %0, hwreg(HW_REG_XCC_ID)" : "=s"(xcc));
    if (tid == 0) {
        AG_STORE(chk + g * 64 + slice, (int)xcc + 1);
        __hip_atomic_fetch_add(chk + 256, 1, __ATOMIC_RELAXED, __HIP_MEMORY_SCOPE_AGENT);
    }

    const int NC = layer ? 32 : 24;
    const int wbytes = NC * 2048;        // 48KB (L1) / 64KB (L2)
    __shared__ char smem[65536];
    {
        const char* wsrc = ws + (layer ? OFF_W2 : OFF_W1)
                         + (size_t)(dir * 64 + slice) * (size_t)wbytes;
        for (int i = tid * 16; i < wbytes; i += 256 * 16)
            *(uint4*)(smem + i) = *(const uint4*)(wsrc + i);
    }
    __syncthreads();

    // runtime zero for fold-proof atomic reads (region zeroed by gather_x, never written)
    unsigned long long zv = *(volatile const unsigned long long*)(ws + OFF_CHK + 2048);

    // wait for all 256 real wgs, then gate the fast path on co-XCD evidence
    int fl0 = 0;
    {
        int it = 0, cnt = 0;
        do { cnt = AG_LOAD(chk + 256); } while (cnt < 256 && ++it < (1 << 20));
        if (cnt >= 256) {
            int my = AG_LOAD(chk + g * 64 + (tid & 63));
            fl0 = (__all(my == __shfl(my, 0, 64)) && (my != 0)) ? 1 : 0;
        }
    }

    const float* bb = layer ? (dir ? b2b : b2f) : (dir ? b1b : b1f);
    if (layer == 0) run_layer<0>(ws, smem, dir, slice, tid, bb, fl0, zv);
    else            run_layer<1>(ws, smem, dir, slice, tid, bb, fl0, zv);
}

// ---------------- phase C: dense head [64,1024]@[1024,5]+bd ----------------
__global__ void head_kernel(const char* __restrict__ ws, const float* __restrict__ Wd,
                            const float* __restrict__ bd, float* __restrict__ out)
{
    int b = blockIdx.x;
    int lane = threadIdx.x;   // 64
    const __bf16* hfF = (const __bf16*)(ws + OFF_HF) + (size_t)b * NH;
    const __bf16* hfB = (const __bf16*)(ws + OFF_HF) + (size_t)(NB * NH) + (size_t)b * NH;
    #pragma unroll
    for (int o = 0; o < 5; ++o) {
        float sum = 0.f;
        for (int k = lane; k < 2 * NH; k += 64) {
            float fv = (k < NH) ? (float)hfF[k] : (float)hfB[k - NH];
            sum += fv * Wd[(size_t)k * 5 + o];
        }
        #pragma unroll
        for (int off = 32; off > 0; off >>= 1) sum += __shfl_down(sum, off, 64);
        if (lane == 0) out[b * 5 + o] = sum + bd[o];
    }
}

// ---------------- launch ----------------
extern "C" void kernel_launch(void* const* d_in, const int* in_sizes, int n_in,
                              void* d_out, int out_size, void* d_ws, size_t ws_size,
                              hipStream_t stream)
{
    const int*   tokens = (const int*)  d_in[0];
    const float* emb    = (const float*)d_in[1];
    const float* W1f    = (const float*)d_in[2];
    const float* U1f    = (const float*)d_in[3];
    const float* b1f    = (const float*)d_in[4];
    const float* W2f    = (const float*)d_in[5];
    const float* U2f    = (const float*)d_in[6];
    const float* b2f    = (const float*)d_in[7];
    const float* W1b    = (const float*)d_in[8];
    const float* U1b    = (const float*)d_in[9];
    const float* b1b    = (const float*)d_in[10];
    const float* W2b    = (const float*)d_in[11];
    const float* U2b    = (const float*)d_in[12];
    const float* b2b    = (const float*)d_in[13];
    const float* Wd     = (const float*)d_in[14];
    const float* bd     = (const float*)d_in[15];
    char* ws = (char*)d_ws;

    wconv_kernel<<<12288, 256, 0, stream>>>(W1f, U1f, W1b, U1b, ws + OFF_W1, 24, 256);
    wconv_kernel<<<16384, 256, 0, stream>>>(W2f, U2f, W2b, U2b, ws + OFF_W2, 32, 512);
    gather_x_kernel<<<32768, 256, 0, stream>>>(tokens, emb, ws);
    lstm_persist<<<512, 256, 0, stream>>>(ws, b1f, b2f, b1b, b2b);
    head_kernel<<<NB, 64, 0, stream>>>(ws, Wd, bd, (float*)d_out);
}

// Round 7
// 3815.232 us; speedup vs baseline: 651.6190x; 5.2573x over previous
//
#include <hip/hip_runtime.h>
#include <hip/hip_bf16.h>

// ---------------- problem constants ----------------
#define TSEQ 512
#define NB   64
#define NE   256
#define NH   512
#define NG   2048   // 4*NH

// ---------------- workspace layout (bytes) ----------------
static const size_t OFF_W1  = 0;          // 6,291,456
static const size_t OFF_W2  = 6291456;    // 8,388,608
static const size_t OFF_X   = 14680064;   // 16,777,216  (fragment-linear per t)
static const size_t OFF_H1  = 31457280;   // 2 dir * 4 slot * 64KB = 524,288 (parity-tagged)
static const size_t OFF_H2  = 31981568;   // 524,288 (parity-tagged, ring 4)
static const size_t OFF_HF  = 32505856;   // 131,072
static const size_t OFF_CNT = 32636928;   // L2 progress tags: x16 replicas, 64 KB

typedef __bf16 v8bf __attribute__((ext_vector_type(8)));
typedef float  v4f  __attribute__((ext_vector_type(4)));

#define MFMA16(a_, b_, c_) __builtin_amdgcn_mfma_f32_16x16x32_bf16((a_), (b_), (c_), 0, 0, 0)

#define AG_LOAD(p)     __hip_atomic_load((p), __ATOMIC_RELAXED, __HIP_MEMORY_SCOPE_AGENT)
#define AG_STORE(p, v) __hip_atomic_store((p), (v), __ATOMIC_RELAXED, __HIP_MEMORY_SCOPE_AGENT)

// Coherent 16B h-fragment load at agent scope (MALL path) — R0..R4 proven.
static __device__ __forceinline__ v8bf load_h8(const __bf16* p) {
    unsigned long long lo = AG_LOAD((unsigned long long*)p);
    unsigned long long hi = AG_LOAD((unsigned long long*)p + 1);
    union { unsigned long long q[2]; v8bf v; } u;
    u.q[0] = lo; u.q[1] = hi;
    return u.v;
}

static __device__ __forceinline__ unsigned short bf16_bits(float f) {
    __bf16 b = (__bf16)f;
    return __builtin_bit_cast(unsigned short, b);
}

// ---- in-band generation-parity validation (R2-proven encoding) ----
// |h| <= 0.99609375 (clamped) => bit14 of every valid bf16 h is 0. Producer ORs
// bit14 = gen parity (gen = s>>2, ring 4). Consumer accepts iff every 16-bit
// half has bit14 == expected parity, then clears bit14 (restores exact bits).
static __device__ __forceinline__ unsigned frag_chk_clr(v8bf* f, unsigned pm) {
    union { v8bf v; unsigned u[4]; } a; a.v = *f;
    unsigned bad = ((a.u[0] ^ pm) | (a.u[1] ^ pm) | (a.u[2] ^ pm) | (a.u[3] ^ pm)) & 0x40004000u;
    a.u[0] &= 0xBFFFBFFFu; a.u[1] &= 0xBFFFBFFFu;
    a.u[2] &= 0xBFFFBFFFu; a.u[3] &= 0xBFFFBFFFu;
    *f = a.v;
    return bad;
}

// Issue 16 speculative fragment loads (no wait — values consumed next step).
#define ISSUE16(sp_, base_)                                                    \
    {                                                                          \
        const __bf16* _b = (base_);                                            \
        _Pragma("unroll")                                                      \
        for (int c = 0; c < 16; ++c)                                           \
            sp_[c] = load_h8(_b + (4 * c + q) * 512 + aoff);                   \
    }

// Validate previously-issued fragments; on failure reload all and re-check.
// Terminates when producers have published (parity algebra, R2-proven).
#define VALIDATE16(sp_, base_, pm_)                                            \
    {                                                                          \
        const __bf16* _b = (base_);                                            \
        const unsigned _pm = (pm_);                                            \
        while (true) {                                                         \
            unsigned _bad = 0u;                                                \
            _Pragma("unroll")                                                  \
            for (int c = 0; c < 16; ++c) _bad |= frag_chk_clr(&sp_[c], _pm);   \
            if (__all(_bad == 0u)) break;                                      \
            _Pragma("unroll")                                                  \
            for (int c = 0; c < 16; ++c)                                       \
                sp_[c] = load_h8(_b + (4 * c + q) * 512 + aoff);               \
            __builtin_amdgcn_sched_barrier(0);                                 \
        }                                                                      \
    }

// ---------------- phase A: weight convert to fragment-linear bf16 ----------------
__global__ void wconv_kernel(const float* __restrict__ Wf, const float* __restrict__ Uf,
                             const float* __restrict__ Wb, const float* __restrict__ Ub,
                             char* __restrict__ dst, int NC, int KX)
{
    int id = blockIdx.x * 256 + threadIdx.x;
    int j    = id & 7;
    int lane = (id >> 3) & 63;
    int t    = (id >> 9) & 1;
    int rest = id >> 10;            // (dir*64+slice)*NC + c
    int c    = rest % NC;
    int ds   = rest / NC;
    int slice = ds & 63;
    int dirr  = ds >> 6;
    int coll = t * 16 + (lane & 15);
    int k    = c * 32 + (lane >> 4) * 8 + j;
    int gate = coll >> 3, jjj = coll & 7;
    int zcol = gate * 512 + slice * 8 + jjj;
    const float* W = dirr ? Wb : Wf;
    const float* U = dirr ? Ub : Uf;
    float v = (k < KX) ? W[(size_t)k * NG + zcol] : U[(size_t)(k - KX) * NG + zcol];
    ((__bf16*)dst)[id] = (__bf16)v;
}

// ---------------- phase A: embedding gather into fragment-linear X + ring/tag init ----------------
__global__ void gather_x_kernel(const int* __restrict__ tokens, const float* __restrict__ emb,
                                char* __restrict__ ws)
{
    size_t id = (size_t)blockIdx.x * 256 + threadIdx.x;
    int j  = (int)(id & 7);
    int m  = (int)((id >> 3) & 63);
    int kb = (int)((id >> 9) & 31);
    int t  = (int)(id >> 14);
    int tok = tokens[m * TSEQ + t];
    float v = emb[(size_t)tok * NE + kb * 8 + j];
    ((__bf16*)(ws + OFF_X))[(size_t)t * 16384 + (kb * 64 + m) * 8 + j] = (__bf16)v;
    // ring init: bit14=1 pattern never validates for generation 0 (parity 0)
    if (id < 262144) ((unsigned*)(ws + OFF_H1))[id] = 0x40004000u;   // H1+H2, both dirs (1MB)
    if (id < 16384)  ((int*)(ws + OFF_CNT))[id] = 0;                 // tag replicas
}

// ---------------- phase B: persistent pipelined recurrence ----------------
// Drain-free, poll-free self-loops: producers store parity-tagged h (bit14 = gen
// parity); consumers issue next-step fragment loads SPECULATIVELY across the
// loop backedge (right after publishing their own h) and validate at use,
// reloading on parity mismatch. The only tag left is L2's progress counter for
// L1's ring-4 overwrite guard (slack 3, prefetched at step top, off-path).
template<int LAYER>
__device__ void run_layer(char* __restrict__ ws, const char* __restrict__ smem,
                          int dir, int slice, int tid,
                          const float* __restrict__ bb)
{
    const int lane = tid & 63;
    const int wv   = tid >> 6;
    const int colc = lane & 15;
    const int q    = lane >> 4;
    const int m0   = wv * 16;
    const int jj   = colc & 7;
    const int hcol = slice * 8 + jj;

    __bf16* h1ring = (__bf16*)(ws + OFF_H1 + (size_t)dir * (4 * 65536));
    __bf16* h2ring = (__bf16*)(ws + OFF_H2 + (size_t)dir * (4 * 65536));
    const char* Xfrag = ws + OFF_X;
    __bf16* hfin = (__bf16*)(ws + OFF_HF) + (size_t)dir * (NB * NH);

    // L2 progress tags (x16 replicas): L2 publishes, L1 polls (ring guard only)
    int* T = (int*)(ws + OFF_CNT);
    const int rep = ((slice << 2) | wv) & 15;
    int* p2   = T + dir * 4096 + rep * 256 + wv * 64 + lane;
    int* ownb = T + dir * 4096;

    const float bi  = bb[hcol];
    const float bf_ = bb[512 + hcol];
    const float bg  = bb[1024 + hcol];
    const float bo  = bb[1536 + hcol];

    float cst[4] = {0.f, 0.f, 0.f, 0.f};
    const int aoff = (m0 + colc) * 8;   // h-fragment element offset (bf16 units)

    v8bf sp0[16];            // L1: h1[s-1] spec | L2: h1[s] spec
    v8bf sp1[16];            // L2 only: h2[s-1] spec

    // L2 pre-issue for step 0 (h1[0], slot 0, parity 0)
    if (LAYER == 1) { ISSUE16(sp0, h1ring); }

    #pragma unroll 1
    for (int s = 0; s < TSEQ; ++s) {
        const unsigned pmC = ((s >> 2) & 1)       ? 0x40004000u : 0u;   // parity of step s
        const unsigned pmP = (((s - 1) >> 2) & 1) ? 0x40004000u : 0u;   // parity of step s-1

        v4f acc0a = {0,0,0,0}, acc1a = {0,0,0,0};
        v4f acc0b = {0,0,0,0}, acc1b = {0,0,0,0};

        // L1: prefetch ring-guard tag at step top (evaluated pre-store, latency hidden)
        int gvG = (LAYER == 0 && s > 3) ? AG_LOAD(p2) : 0x7fffffff;

        if (LAYER == 0) {
            // ---- x-part (no step dependency) — fills the speculative loads' flight time ----
            const int xs = dir ? (TSEQ - 1 - s) : s;
            const char* xb = Xfrag + (size_t)xs * 32768;
            #pragma unroll
            for (int c = 0; c < 8; ++c) {
                v8bf a  = *(const v8bf*)(xb + (((4 * c + q) * 64 + m0 + colc) * 16));
                v8bf w0 = *(const v8bf*)(smem + (c * 2 + 0) * 1024 + lane * 16);
                v8bf w1 = *(const v8bf*)(smem + (c * 2 + 1) * 1024 + lane * 16);
                if (c & 1) { acc0b = MFMA16(a, w0, acc0b); acc1b = MFMA16(a, w1, acc1b); }
                else       { acc0a = MFMA16(a, w0, acc0a); acc1a = MFMA16(a, w1, acc1a); }
            }
            // ---- h1[s-1]: validate speculative fragments, then MFMA ----
            if (s > 0) {
                VALIDATE16(sp0, h1ring + (size_t)((s - 1) & 3) * 32768, pmP);
                __builtin_amdgcn_sched_barrier(0);
                #pragma unroll
                for (int c = 0; c < 16; ++c) {
                    v8bf w0 = *(const v8bf*)(smem + ((8 + c) * 2 + 0) * 1024 + lane * 16);
                    v8bf w1 = *(const v8bf*)(smem + ((8 + c) * 2 + 1) * 1024 + lane * 16);
                    if (c & 1) { acc0b = MFMA16(sp0[c], w0, acc0b); acc1b = MFMA16(sp0[c], w1, acc1b); }
                    else       { acc0a = MFMA16(sp0[c], w0, acc0a); acc1a = MFMA16(sp0[c], w1, acc1a); }
                }
            }
        } else {
            // ---- h1[s]: validate speculative fragments (L1 runs ahead; usually instant) ----
            VALIDATE16(sp0, h1ring + (size_t)(s & 3) * 32768, pmC);
            __builtin_amdgcn_sched_barrier(0);
            #pragma unroll
            for (int c = 0; c < 16; ++c) {
                v8bf w0 = *(const v8bf*)(smem + (c * 2 + 0) * 1024 + lane * 16);
                v8bf w1 = *(const v8bf*)(smem + (c * 2 + 1) * 1024 + lane * 16);
                if (c & 1) { acc0b = MFMA16(sp0[c], w0, acc0b); acc1b = MFMA16(sp0[c], w1, acc1b); }
                else       { acc0a = MFMA16(sp0[c], w0, acc0a); acc1a = MFMA16(sp0[c], w1, acc1a); }
            }
            // ---- h2[s-1]: the zero-slack self-loop — validated speculative ----
            if (s > 0) {
                VALIDATE16(sp1, h2ring + (size_t)((s - 1) & 3) * 32768, pmP);
                __builtin_amdgcn_sched_barrier(0);
                #pragma unroll
                for (int c = 0; c < 16; ++c) {
                    v8bf w0 = *(const v8bf*)(smem + ((16 + c) * 2 + 0) * 1024 + lane * 16);
                    v8bf w1 = *(const v8bf*)(smem + ((16 + c) * 2 + 1) * 1024 + lane * 16);
                    if (c & 1) { acc0b = MFMA16(sp1[c], w0, acc0b); acc1b = MFMA16(sp1[c], w1, acc1b); }
                    else       { acc0a = MFMA16(sp1[c], w0, acc0a); acc1a = MFMA16(sp1[c], w1, acc1a); }
                }
            }
        }

        v4f z0 = acc0a + acc0b;   // gates i (cols 0-7) / f (cols 8-15)
        v4f z1 = acc1a + acc1b;   // gates g / o

        // ---- gate nonlinearity; lanes col and col^8 exchange ----
        float hv[4];
        #pragma unroll
        for (int r = 0; r < 4; ++r) {
            float p0 = __shfl_xor(z0[r], 8, 64);
            float p1 = __shfl_xor(z1[r], 8, 64);
            float zi, zf, zg, zo;
            if (colc < 8) { zi = z0[r]; zf = p0;    zg = z1[r]; zo = p1;    }
            else          { zi = p0;    zf = z0[r]; zg = p1;    zo = z1[r]; }
            zi += bi; zf += bf_; zg += bg; zo += bo;
            float gi = 1.f / (1.f + __expf(-zi));
            float gf = 1.f / (1.f + __expf(-zf));
            float gg = 1.f - 2.f / (1.f + __expf(2.f * zg));   // tanh
            float go = 1.f / (1.f + __expf(-zo));
            float cn = gf * cst[r] + gi * gg;
            cst[r] = cn;
            float th = 1.f - 2.f / (1.f + __expf(2.f * cn));   // tanh
            // clamp to largest bf16 < 1.0: keeps bit14 == 0 (parity-tag invariant);
            // acts only when |h| >= 0.998 (~12 sigma), error <= 0.004 if ever hit
            hv[r] = fminf(fmaxf(go * th, -0.99609375f), 0.99609375f);
        }

        // ---- L1 ring-4 guard: L2 must have completed step s-4 (tag >= s-3) ----
        if (LAYER == 0 && s > 3 && !__all(gvG >= s - 3)) {
            while (true) {
                int v2 = AG_LOAD(p2);
                if (__all(v2 >= s - 3)) break;
            }
        }

        // ---- coalesced parity-tagged publication (R4 transpose; drain-free) ----
        __bf16* hd = (LAYER ? h2ring : h1ring) + (size_t)(s & 3) * 32768;
        {
            unsigned u0, u1, u2, u3;
            {
                float pv0 = __shfl_xor(hv[0], 1, 64);
                float pv1 = __shfl_xor(hv[1], 1, 64);
                float pv2 = __shfl_xor(hv[2], 1, 64);
                float pv3 = __shfl_xor(hv[3], 1, 64);
                u0 = (unsigned)bf16_bits(hv[0]) | ((unsigned)bf16_bits(pv0) << 16);
                u1 = (unsigned)bf16_bits(hv[1]) | ((unsigned)bf16_bits(pv1) << 16);
                u2 = (unsigned)bf16_bits(hv[2]) | ((unsigned)bf16_bits(pv2) << 16);
                u3 = (unsigned)bf16_bits(hv[3]) | ((unsigned)bf16_bits(pv3) << 16);
            }
            const bool sel1 = (colc & 2) != 0;
            const bool sel2 = (colc & 4) != 0;
            unsigned t;
            t = __shfl_xor(sel1 ? u0 : u1, 2, 64); if (sel1) u0 = t; else u1 = t;
            t = __shfl_xor(sel1 ? u2 : u3, 2, 64); if (sel1) u2 = t; else u3 = t;
            t = __shfl_xor(sel2 ? u0 : u2, 4, 64); if (sel2) u0 = t; else u2 = t;
            t = __shfl_xor(sel2 ? u1 : u3, 4, 64); if (sel2) u1 = t; else u3 = t;
            if (((colc & 1) == 0) && (colc < 8)) {
                const int m = m0 + q * 4 + (colc >> 1);
                const unsigned long long pm64 = pmC ? 0x4000400040004000ULL : 0ULL;
                unsigned long long lo = ((unsigned long long)u0 | ((unsigned long long)u1 << 32)) | pm64;
                unsigned long long hi = ((unsigned long long)u2 | ((unsigned long long)u3 << 32)) | pm64;
                unsigned long long* dp = (unsigned long long*)(hd + (slice * 64 + m) * 8);
                AG_STORE(dp,     lo);
                AG_STORE(dp + 1, hi);
            }
        }
        if (LAYER == 1 && s == TSEQ - 1 && colc < 8) {
            #pragma unroll
            for (int r = 0; r < 4; ++r)
                hfin[(size_t)(m0 + q * 4 + r) * NH + hcol] = (__bf16)hv[r];   // kernel boundary
        }

        // ---- L2 progress tag (drain-free: consumption already completed in-regs) ----
        if (LAYER == 1 && lane < 16)
            AG_STORE(ownb + lane * 256 + wv * 64 + slice, s + 1);

        // ---- speculative issue for the NEXT step (the overlap lever) ----
        __builtin_amdgcn_sched_barrier(0);
        if (s < TSEQ - 1) {
            if (LAYER == 0) {
                ISSUE16(sp0, h1ring + (size_t)(s & 3) * 32768);           // h1[s] for step s+1
            } else {
                ISSUE16(sp0, h1ring + (size_t)((s + 1) & 3) * 32768);     // h1[s+1]
                ISSUE16(sp1, h2ring + (size_t)(s & 3) * 32768);           // h2[s]
            }
        }
        __builtin_amdgcn_sched_barrier(0);
    }
}

__global__ __launch_bounds__(256, 1) void lstm_persist(
    char* __restrict__ ws,
    const float* __restrict__ b1f, const float* __restrict__ b2f,
    const float* __restrict__ b1b, const float* __restrict__ b2b)
{
    const int tid   = threadIdx.x;
    const int bid   = blockIdx.x;       // 256 wgs
    const int dir   = bid >> 7;
    const int layer = (bid >> 6) & 1;
    const int slice = bid & 63;

    const int NC = layer ? 32 : 24;
    const int wbytes = NC * 2048;       // 48KB (L1) / 64KB (L2)

    __shared__ char smem[65536];
    {
        const char* wsrc = ws + (layer ? OFF_W2 : OFF_W1)
                         + (size_t)(dir * 64 + slice) * (size_t)wbytes;
        for (int i = tid * 16; i < wbytes; i += 256 * 16)
            *(uint4*)(smem + i) = *(const uint4*)(wsrc + i);
    }
    __syncthreads();   // staging is cooperative; only barrier in the kernel

    const float* bb = layer ? (dir ? b2b : b2f) : (dir ? b1b : b1f);
    if (layer == 0) run_layer<0>(ws, smem, dir, slice, tid, bb);
    else            run_layer<1>(ws, smem, dir, slice, tid, bb);
}

// ---------------- phase C: dense head [64,1024]@[1024,5]+bd ----------------
__global__ void head_kernel(const char* __restrict__ ws, const float* __restrict__ Wd,
                            const float* __restrict__ bd, float* __restrict__ out)
{
    int b = blockIdx.x;
    int lane = threadIdx.x;   // 64
    const __bf16* hfF = (const __bf16*)(ws + OFF_HF) + (size_t)b * NH;
    const __bf16* hfB = (const __bf16*)(ws + OFF_HF) + (size_t)(NB * NH) + (size_t)b * NH;
    #pragma unroll
    for (int o = 0; o < 5; ++o) {
        float sum = 0.f;
        for (int k = lane; k < 2 * NH; k += 64) {
            float fv = (k < NH) ? (float)hfF[k] : (float)hfB[k - NH];
            sum += fv * Wd[(size_t)k * 5 + o];
        }
        #pragma unroll
        for (int off = 32; off > 0; off >>= 1) sum += __shfl_down(sum, off, 64);
        if (lane == 0) out[b * 5 + o] = sum + bd[o];
    }
}

// ---------------- launch ----------------
extern "C" void kernel_launch(void* const* d_in, const int* in_sizes, int n_in,
                              void* d_out, int out_size, void* d_ws, size_t ws_size,
                              hipStream_t stream)
{
    const int*   tokens = (const int*)  d_in[0];
    const float* emb    = (const float*)d_in[1];
    const float* W1f    = (const float*)d_in[2];
    const float* U1f    = (const float*)d_in[3];
    const float* b1f    = (const float*)d_in[4];
    const float* W2f    = (const float*)d_in[5];
    const float* U2f    = (const float*)d_in[6];
    const float* b2f    = (const float*)d_in[7];
    const float* W1b    = (const float*)d_in[8];
    const float* U1b    = (const float*)d_in[9];
    const float* b1b    = (const float*)d_in[10];
    const float* W2b    = (const float*)d_in[11];
    const float* U2b    = (const float*)d_in[12];
    const float* b2b    = (const float*)d_in[13];
    const float* Wd     = (const float*)d_in[14];
    const float* bd     = (const float*)d_in[15];
    char* ws = (char*)d_ws;

    wconv_kernel<<<12288, 256, 0, stream>>>(W1f, U1f, W1b, U1b, ws + OFF_W1, 24, 256);
    wconv_kernel<<<16384, 256, 0, stream>>>(W2f, U2f, W2b, U2b, ws + OFF_W2, 32, 512);
    gather_x_kernel<<<32768, 256, 0, stream>>>(tokens, emb, ws);
    lstm_persist<<<256, 256, 0, stream>>>(ws, b1f, b2f, b1b, b2b);
    head_kernel<<<NB, 64, 0, stream>>>(ws, Wd, bd, (float*)d_out);
}